// Round 1
// baseline (1750.716 us; speedup 1.0000x reference)
//
#include <hip/hip_runtime.h>

// RNN scan: h <- tanh(x_t @ W_ih^T + h @ W_hh^T + b_ih + b_hh), 2048 steps.
// One block per batch element (256 blocks, 1/CU). 256 threads: t = 2j+p,
// thread computes half (64 MACs) of each of the two dots for output j.
// W rows live in registers (128 VGPR/thread); x_t / h are LDS broadcast reads.
// h double-buffered -> single barrier per step. x staged in 16-step chunks,
// prefetched one chunk ahead through registers.

#define BATCH 256
#define SEQ   2048
#define HID   128
#define CH    16
#define NCHUNK (SEQ / CH)

__global__ __launch_bounds__(256, 1) void rnn_scan_kernel(
    const float* __restrict__ x,    // [B, S, 128]
    const float* __restrict__ Wih,  // [128, 128]
    const float* __restrict__ bih,  // [128]
    const float* __restrict__ Whh,  // [128, 128]
    const float* __restrict__ bhh,  // [128]
    float* __restrict__ out)        // [B, 128]
{
    const int b = blockIdx.x;
    const int t = threadIdx.x;
    const int j = t >> 1;      // output index 0..127
    const int p = t & 1;       // half: 0 -> cols [0,64), 1 -> cols [64,128)
    const int off = p * 64;

    __shared__ __align__(16) float xbuf[2][CH * HID]; // 2 x 8 KB
    __shared__ __align__(16) float hbuf[2][HID];      // double-buffered h

    // --- W rows into registers: 32 float4 = 128 VGPRs ---
    float4 wi[16], wh[16];
    {
        const float4* wip = reinterpret_cast<const float4*>(Wih + j * HID + off);
        const float4* whp = reinterpret_cast<const float4*>(Whh + j * HID + off);
#pragma unroll
        for (int k = 0; k < 16; ++k) { wi[k] = wip[k]; wh[k] = whp[k]; }
    }
    const float bsum = bih[j] + bhh[j];

    const float* xsrc = x + (size_t)b * (SEQ * HID);

    // --- prologue: stage chunk 0, zero h ---
    {
        const float4* g = reinterpret_cast<const float4*>(xsrc);
        float4 p0 = g[t];
        float4 p1 = g[256 + t];
        float4* lb = reinterpret_cast<float4*>(&xbuf[0][0]);
        lb[t] = p0;
        lb[256 + t] = p1;
    }
    if (t < HID) hbuf[0][t] = 0.0f;
    __syncthreads();

    int hcur = 0;
    for (int c = 0; c < NCHUNK; ++c) {
        // prefetch next chunk into registers (consumed at s == CH-1)
        float4 q0, q1;
        const bool pf = (c + 1 < NCHUNK);
        if (pf) {
            const float4* g =
                reinterpret_cast<const float4*>(xsrc + (size_t)(c + 1) * (CH * HID));
            q0 = g[t];
            q1 = g[256 + t];
        }
        const float* xb = &xbuf[c & 1][0];
#pragma unroll 1
        for (int s = 0; s < CH; ++s) {
            const float* xr = xb + s * HID + off;
            const float* hr = &hbuf[hcur][off];
            float a0 = 0.f, a1 = 0.f, a2 = 0.f, a3 = 0.f;
#pragma unroll
            for (int k = 0; k < 16; ++k) {
                float4 xv = *reinterpret_cast<const float4*>(xr + 4 * k);
                a0 = fmaf(wi[k].x, xv.x, a0);
                a1 = fmaf(wi[k].y, xv.y, a1);
                a2 = fmaf(wi[k].z, xv.z, a2);
                a3 = fmaf(wi[k].w, xv.w, a3);
            }
#pragma unroll
            for (int k = 0; k < 16; ++k) {
                float4 hv = *reinterpret_cast<const float4*>(hr + 4 * k);
                a0 = fmaf(wh[k].x, hv.x, a0);
                a1 = fmaf(wh[k].y, hv.y, a1);
                a2 = fmaf(wh[k].z, hv.z, a2);
                a3 = fmaf(wh[k].w, hv.w, a3);
            }
            float acc = (a0 + a1) + (a2 + a3);
            acc += __shfl_xor(acc, 1, 64);   // combine the two halves (same wave)
            if (p == 0) {
                float pre = acc + bsum;
                pre = fminf(fmaxf(pre, -15.0f), 15.0f);
                float e = __expf(2.0f * pre);
                float th = (e - 1.0f) / (e + 1.0f);   // tanh(pre)
                hbuf[hcur ^ 1][j] = th;
            }
            if (s == CH - 1 && pf) {
                float4* lb = reinterpret_cast<float4*>(&xbuf[(c + 1) & 1][0]);
                lb[t] = q0;           // vmcnt wait lands here: ~15 steps of slack
                lb[256 + t] = q1;
            }
            __syncthreads();
            hcur ^= 1;
        }
    }
    // after 2048 toggles hcur is back to 0 and holds h_final
    if (t < HID) out[(size_t)b * HID + t] = hbuf[hcur][t];
}

extern "C" void kernel_launch(void* const* d_in, const int* in_sizes, int n_in,
                              void* d_out, int out_size, void* d_ws, size_t ws_size,
                              hipStream_t stream) {
    const float* x   = (const float*)d_in[0];
    const float* Wih = (const float*)d_in[1];
    const float* bih = (const float*)d_in[2];
    const float* Whh = (const float*)d_in[3];
    const float* bhh = (const float*)d_in[4];
    float* out = (float*)d_out;

    rnn_scan_kernel<<<BATCH, 256, 0, stream>>>(x, Wih, bih, Whh, bhh, out);
}

// Round 2
// 1313.227 us; speedup vs baseline: 1.3331x; 1.3331x over previous
//
#include <hip/hip_runtime.h>

// RNN scan: h <- tanh(x_t @ W_ih^T + h @ W_hh^T + b), 2048 steps, 1 block/batch.
// 256 threads = 16 row-groups x 16 col-groups. Thread (g,c) owns rows 8g..8g+7,
// cols 8c..8c+7 of BOTH W matrices in registers (128 VGPRs). Per step:
// 4 ds_read_b128 (x cols + h cols) + 128 v_fmac + DPP-only 16-lane reduction
// (no LDS-pipe shuffles) + 1 predicated ds_write_b64 + 1 barrier.
// h double-buffered with +4/8-rows padding -> 2-way (free) bank aliasing.

#define BATCH 256
#define SEQ   2048
#define HID   128
#define CH    16
#define NCHUNK (SEQ / CH)

// DPP ctrl: quad_perm[1,0,3,2]=0xB1 (xor1), quad_perm[2,3,0,1]=0x4E (xor2),
// row_ror:4=0x124, row_ror:8=0x128 (rows of 16 lanes on gfx9+)
template <int CTRL>
__device__ __forceinline__ float dpp_movf(float x) {
    return __int_as_float(__builtin_amdgcn_mov_dpp(__float_as_int(x), CTRL, 0xF, 0xF, true));
}

__device__ __forceinline__ float tanh_fast(float x) {
    x = fminf(fmaxf(x, -12.0f), 12.0f);
    float e = __expf(2.0f * x);
    return 1.0f - __fdividef(2.0f, e + 1.0f);
}

__global__ __launch_bounds__(256, 1) void rnn_scan_kernel(
    const float* __restrict__ x,    // [B, S, 128]
    const float* __restrict__ Wih,  // [128, 128]
    const float* __restrict__ bih,  // [128]
    const float* __restrict__ Whh,  // [128, 128]
    const float* __restrict__ bhh,  // [128]
    float* __restrict__ out)        // [B, 128]
{
    const int b = blockIdx.x;
    const int t = threadIdx.x;
    const int g = t >> 4;          // row group: rows 8g..8g+7
    const int c = t & 15;          // col group: cols 8c..8c+7
    const int colbase = c << 3;
    const int rowbase = g << 3;

    __shared__ __align__(16) float xbuf[2][CH * HID];  // 2 x 8 KB
    __shared__ __align__(16) float hbuf[2][192];       // padded: p(r) = r + 4*(r>>3)

    // --- W tiles into registers: 8 rows x 8 cols x 2 mats = 128 VGPRs ---
    float4 wi[8][2], wh[8][2];
#pragma unroll
    for (int r = 0; r < 8; ++r) {
        const float* pi = Wih + (rowbase + r) * HID + colbase;
        const float* ph = Whh + (rowbase + r) * HID + colbase;
        wi[r][0] = *(const float4*)(pi);
        wi[r][1] = *(const float4*)(pi + 4);
        wh[r][0] = *(const float4*)(ph);
        wh[r][1] = *(const float4*)(ph + 4);
    }

    // reduce-scatter row assignment: lane c ends with rows 8g+o, 8g+o+1
    const int m = c & 3;
    const int o = ((m & 1) << 2) | (m & 2);   // 0,4,2,6 for m=0..3
    const int row0 = rowbase + o;
    const float bias0 = bih[row0] + bhh[row0];
    const float bias1 = bih[row0 + 1] + bhh[row0 + 1];
    const int hw = row0 + (g << 2);           // padded index of row0 (even)

    const float* xsrc = x + (size_t)b * (SEQ * HID);

    // --- prologue: stage chunk 0, zero h ---
    {
        const float4* gp = (const float4*)xsrc;
        float4 p0 = gp[t];
        float4 p1 = gp[256 + t];
        float4* lb = (float4*)&xbuf[0][0];
        lb[t] = p0;
        lb[256 + t] = p1;
    }
    if (t < 192) hbuf[0][t] = 0.0f;
    __syncthreads();

    int cur = 0;
    for (int chn = 0; chn < NCHUNK; ++chn) {
        float4 q0, q1;
        const bool pf = (chn + 1 < NCHUNK);
        if (pf) {
            const float4* gp = (const float4*)(xsrc + (size_t)(chn + 1) * (CH * HID));
            q0 = gp[t];
            q1 = gp[256 + t];
        }
        const float* xb = &xbuf[chn & 1][0];
#pragma unroll 1
        for (int s = 0; s < CH; ++s) {
            const float* xr = xb + s * HID + colbase;
            const float* hr = &hbuf[cur][12 * c];  // p(8c) = 12c, 16B-aligned
            float4 xv0 = *(const float4*)(xr);
            float4 xv1 = *(const float4*)(xr + 4);
            float4 hv0 = *(const float4*)(hr);
            float4 hv1 = *(const float4*)(hr + 4);

            float a[8];
#pragma unroll
            for (int r = 0; r < 8; ++r) {
                float acc;
                acc = wi[r][0].x * xv0.x;
                acc = fmaf(wi[r][0].y, xv0.y, acc);
                acc = fmaf(wi[r][0].z, xv0.z, acc);
                acc = fmaf(wi[r][0].w, xv0.w, acc);
                acc = fmaf(wi[r][1].x, xv1.x, acc);
                acc = fmaf(wi[r][1].y, xv1.y, acc);
                acc = fmaf(wi[r][1].z, xv1.z, acc);
                acc = fmaf(wi[r][1].w, xv1.w, acc);
                acc = fmaf(wh[r][0].x, hv0.x, acc);
                acc = fmaf(wh[r][0].y, hv0.y, acc);
                acc = fmaf(wh[r][0].z, hv0.z, acc);
                acc = fmaf(wh[r][0].w, hv0.w, acc);
                acc = fmaf(wh[r][1].x, hv1.x, acc);
                acc = fmaf(wh[r][1].y, hv1.y, acc);
                acc = fmaf(wh[r][1].z, hv1.z, acc);
                acc = fmaf(wh[r][1].w, hv1.w, acc);
                a[r] = acc;
            }

            // --- DPP reduce-scatter over the 16-lane col dimension ---
            const bool b0 = (c & 1) != 0;
            const bool b1 = (c & 2) != 0;
            // round 1: xor 1 (quad_perm), scatter rows +-4
            float k0 = b0 ? a[4] : a[0], g0 = b0 ? a[0] : a[4];
            float k1 = b0 ? a[5] : a[1], g1 = b0 ? a[1] : a[5];
            float k2 = b0 ? a[6] : a[2], g2 = b0 ? a[2] : a[6];
            float k3 = b0 ? a[7] : a[3], g3 = b0 ? a[3] : a[7];
            float t0 = k0 + dpp_movf<0xB1>(g0);
            float t1 = k1 + dpp_movf<0xB1>(g1);
            float t2 = k2 + dpp_movf<0xB1>(g2);
            float t3 = k3 + dpp_movf<0xB1>(g3);
            // round 2: xor 2 (quad_perm), scatter rows +-2
            float k4 = b1 ? t2 : t0, g4 = b1 ? t0 : t2;
            float k5 = b1 ? t3 : t1, g5 = b1 ? t1 : t3;
            float u0 = k4 + dpp_movf<0x4E>(g4);
            float u1 = k5 + dpp_movf<0x4E>(g5);
            // rounds 3,4: all-reduce over lanes {c, c+4, c+8, c+12} via row_ror
            u0 += dpp_movf<0x124>(u0);
            u1 += dpp_movf<0x124>(u1);
            u0 += dpp_movf<0x128>(u0);
            u1 += dpp_movf<0x128>(u1);

            float h0 = tanh_fast(u0 + bias0);
            float h1 = tanh_fast(u1 + bias1);
            if (c < 4) {  // lanes c>=4 hold duplicates
                *(float2*)&hbuf[cur ^ 1][hw] = make_float2(h0, h1);
            }

            if (s == CH - 1 && pf) {
                float4* lb = (float4*)&xbuf[(chn + 1) & 1][0];
                lb[t] = q0;
                lb[256 + t] = q1;
            }
            __syncthreads();
            cur ^= 1;
        }
    }
    // cur == 0 after 2048 toggles; hbuf[0] holds h_final (padded layout)
    if (t < HID) out[(size_t)b * HID + t] = hbuf[cur][t + ((t >> 3) << 2)];
}

extern "C" void kernel_launch(void* const* d_in, const int* in_sizes, int n_in,
                              void* d_out, int out_size, void* d_ws, size_t ws_size,
                              hipStream_t stream) {
    const float* x   = (const float*)d_in[0];
    const float* Wih = (const float*)d_in[1];
    const float* bih = (const float*)d_in[2];
    const float* Whh = (const float*)d_in[3];
    const float* bhh = (const float*)d_in[4];
    float* out = (float*)d_out;

    rnn_scan_kernel<<<BATCH, 256, 0, stream>>>(x, Wih, bih, Whh, bhh, out);
}